// Round 1
// baseline (1901.122 us; speedup 1.0000x reference)
//
#include <hip/hip_runtime.h>

#define F 64

// ---- degree count: deg_edges[v] = #edges with dst==v ----
__global__ __launch_bounds__(256) void count_deg(const int* __restrict__ dst,
                                                 unsigned* __restrict__ cnt, int E) {
    int e = blockIdx.x * 256 + threadIdx.x;
    if (e < E) atomicAdd(&cnt[dst[e]], 1u);
}

// ---- dinv[v] = rsqrt(deg_edges[v] + 1)  (self-loop included) ----
__global__ __launch_bounds__(256) void make_dinv(const unsigned* __restrict__ cnt,
                                                 float* __restrict__ dinv, int N) {
    int v = blockIdx.x * 256 + threadIdx.x;
    if (v < N) dinv[v] = rsqrtf((float)(cnt[v] + 1u));
}

// ---- Y[N,64] = X[N,64] @ W[64,64], fp32 vector ALU ----
// block = 256 threads, 16 rows/block; W (16 KB) + X-tile (4 KB) in LDS.
__global__ __launch_bounds__(256) void mm64(const float* __restrict__ X,
                                            const float* __restrict__ W,
                                            float* __restrict__ Y, int N) {
    __shared__ float Ws[64 * 64];
    __shared__ float Xs[16 * 64];
    int tid = threadIdx.x;
    // stage W: 4096 floats = 1024 float4
    for (int i = tid; i < 1024; i += 256)
        ((float4*)Ws)[i] = ((const float4*)W)[i];
    int row0 = blockIdx.x * 16;
    {   // stage 16 rows of X: 256 float4, one per thread
        int r = tid >> 4, c4 = tid & 15;
        int grow = row0 + r;
        float4 v = make_float4(0.f, 0.f, 0.f, 0.f);
        if (grow < N) v = ((const float4*)(X + (size_t)grow * F))[c4];
        ((float4*)Xs)[tid] = v;
    }
    __syncthreads();
    int r = tid >> 4, c = (tid & 15) * 4;
    float4 acc = make_float4(0.f, 0.f, 0.f, 0.f);
#pragma unroll
    for (int k = 0; k < 64; ++k) {
        float xv = Xs[r * 64 + k];
        float4 w = *(const float4*)&Ws[k * 64 + c];
        acc.x += xv * w.x; acc.y += xv * w.y;
        acc.z += xv * w.z; acc.w += xv * w.w;
    }
    int grow = row0 + r;
    if (grow < N) *(float4*)(Y + (size_t)grow * F + c) = acc;
}

// ---- edge scatter: O[dst] += H[src] * dinv[src]*dinv[dst] ----
// 16 lanes per edge, float4 gather + 4 scalar atomics per lane.
__global__ __launch_bounds__(256) void agg_edges(const int* __restrict__ src,
                                                 const int* __restrict__ dst,
                                                 const float* __restrict__ dinv,
                                                 const float* __restrict__ H,
                                                 float* __restrict__ O, int E) {
    int gid = blockIdx.x * 256 + threadIdx.x;
    int e = gid >> 4;
    if (e >= E) return;
    int f4 = gid & 15;
    int s = src[e], d = dst[e];
    float nrm = dinv[s] * dinv[d];
    float4 h = ((const float4*)(H + (size_t)s * F))[f4];
    float* o = O + (size_t)d * F + f4 * 4;
    atomicAdd(o + 0, h.x * nrm);
    atomicAdd(o + 1, h.y * nrm);
    atomicAdd(o + 2, h.z * nrm);
    atomicAdd(o + 3, h.w * nrm);
}

// ---- self-loop + bias (+optional ReLU): O = act(O + H*dinv^2 + b) ----
template <int RELU>
__global__ __launch_bounds__(256) void self_bias(const float* __restrict__ H,
                                                 const float* __restrict__ dinv,
                                                 const float* __restrict__ b,
                                                 float* __restrict__ O, int N) {
    int gid = blockIdx.x * 256 + threadIdx.x;  // over N*16 float4s
    if (gid >= N * 16) return;
    int v = gid >> 4, f4 = gid & 15;
    float di = dinv[v];
    float w = di * di;
    float4 h = ((const float4*)(H + (size_t)v * F))[f4];
    float4 o = ((const float4*)(O + (size_t)v * F))[f4];
    float4 bb = ((const float4*)b)[f4];
    float4 r;
    r.x = o.x + h.x * w + bb.x;
    r.y = o.y + h.y * w + bb.y;
    r.z = o.z + h.z * w + bb.z;
    r.w = o.w + h.w * w + bb.w;
    if (RELU) {
        r.x = fmaxf(r.x, 0.f); r.y = fmaxf(r.y, 0.f);
        r.z = fmaxf(r.z, 0.f); r.w = fmaxf(r.w, 0.f);
    }
    ((float4*)(O + (size_t)v * F))[f4] = r;
}

extern "C" void kernel_launch(void* const* d_in, const int* in_sizes, int n_in,
                              void* d_out, int out_size, void* d_ws, size_t ws_size,
                              hipStream_t stream) {
    const float* x  = (const float*)d_in[0];
    const int*   ei = (const int*)d_in[1];
    const float* W1 = (const float*)d_in[2];
    const float* b1 = (const float*)d_in[3];
    const float* W2 = (const float*)d_in[4];
    const float* b2 = (const float*)d_in[5];
    int N = in_sizes[0] / F;
    int E = in_sizes[1] / 2;
    const int* srcp = ei;
    const int* dstp = ei + E;
    float* out = (float*)d_out;

    // workspace layout (all 256B aligned): cnt[N u32] | dinv[N f32] | bufA | bufB
    char* w = (char*)d_ws;
    size_t nAl = (((size_t)N * 4) + 255) / 256 * 256;
    unsigned* cnt  = (unsigned*)w;
    float*    dinv = (float*)(w + nAl);
    float*    bufA = (float*)(w + 2 * nAl);                 // h1, later h2
    float*    bufB = bufA + (size_t)N * F;                  // layer-1 output

    size_t featBytes = (size_t)N * F * sizeof(float);
    hipMemsetAsync(cnt, 0, (size_t)N * 4, stream);
    hipMemsetAsync(bufB, 0, featBytes, stream);
    hipMemsetAsync(out, 0, featBytes, stream);

    count_deg<<<(E + 255) / 256, 256, 0, stream>>>(dstp, cnt, E);
    make_dinv<<<(N + 255) / 256, 256, 0, stream>>>(cnt, dinv, N);

    // layer 1
    mm64<<<(N + 15) / 16, 256, 0, stream>>>(x, W1, bufA, N);
    agg_edges<<<((size_t)E * 16 + 255) / 256, 256, 0, stream>>>(srcp, dstp, dinv, bufA, bufB, E);
    self_bias<1><<<((size_t)N * 16 + 255) / 256, 256, 0, stream>>>(bufA, dinv, b1, bufB, N);

    // layer 2
    mm64<<<(N + 15) / 16, 256, 0, stream>>>(bufB, W2, bufA, N);
    agg_edges<<<((size_t)E * 16 + 255) / 256, 256, 0, stream>>>(srcp, dstp, dinv, bufA, out, E);
    self_bias<0><<<((size_t)N * 16 + 255) / 256, 256, 0, stream>>>(bufA, dinv, b2, out, N);
}

// Round 2
// 327.208 us; speedup vs baseline: 5.8101x; 5.8101x over previous
//
#include <hip/hip_runtime.h>

#define F 64
#define SCAN_BLOCK 256
#define SCAN_ELEMS 1024  // 4 elements per thread

// ---- degree count: cnt[v] = #edges with dst==v ----
__global__ __launch_bounds__(256) void count_deg(const int* __restrict__ dst,
                                                 unsigned* __restrict__ cnt, int E) {
    int e = blockIdx.x * 256 + threadIdx.x;
    if (e < E) atomicAdd(&cnt[dst[e]], 1u);
}

// ---- dinv[v] = rsqrt(cnt[v] + 1)  (self-loop included) ----
__global__ __launch_bounds__(256) void make_dinv(const unsigned* __restrict__ cnt,
                                                 float* __restrict__ dinv, int N) {
    int v = blockIdx.x * 256 + threadIdx.x;
    if (v < N) dinv[v] = rsqrtf((float)(cnt[v] + 1u));
}

// ---- scan stage 1: per-block exclusive scan of cnt -> rowptr, block totals -> bsum ----
__global__ __launch_bounds__(SCAN_BLOCK) void scan1(const unsigned* __restrict__ cnt,
                                                    unsigned* __restrict__ rowptr,
                                                    unsigned* __restrict__ bsum, int N) {
    __shared__ unsigned ts[SCAN_BLOCK];
    int t = threadIdx.x;
    int base = blockIdx.x * SCAN_ELEMS + t * 4;
    unsigned v0 = 0, v1 = 0, v2 = 0, v3 = 0;
    if (base + 0 < N) v0 = cnt[base + 0];
    if (base + 1 < N) v1 = cnt[base + 1];
    if (base + 2 < N) v2 = cnt[base + 2];
    if (base + 3 < N) v3 = cnt[base + 3];
    ts[t] = v0 + v1 + v2 + v3;
    __syncthreads();
    // inclusive Hillis-Steele over thread sums
    for (int off = 1; off < SCAN_BLOCK; off <<= 1) {
        unsigned add = (t >= off) ? ts[t - off] : 0u;
        __syncthreads();
        ts[t] += add;
        __syncthreads();
    }
    unsigned excl = (t == 0) ? 0u : ts[t - 1];
    if (t == SCAN_BLOCK - 1) bsum[blockIdx.x] = ts[t];
    if (base + 0 < N) rowptr[base + 0] = excl;
    if (base + 1 < N) rowptr[base + 1] = excl + v0;
    if (base + 2 < N) rowptr[base + 2] = excl + v0 + v1;
    if (base + 3 < N) rowptr[base + 3] = excl + v0 + v1 + v2;
}

// ---- scan stage 2: exclusive scan of block sums (nb <= 256), in place ----
__global__ __launch_bounds__(256) void scan2(unsigned* __restrict__ bsum, int nb) {
    __shared__ unsigned ts[256];
    int t = threadIdx.x;
    ts[t] = (t < nb) ? bsum[t] : 0u;
    __syncthreads();
    for (int off = 1; off < 256; off <<= 1) {
        unsigned add = (t >= off) ? ts[t - off] : 0u;
        __syncthreads();
        ts[t] += add;
        __syncthreads();
    }
    unsigned excl = (t == 0) ? 0u : ts[t - 1];
    if (t < nb) bsum[t] = excl;
}

// ---- scan stage 3: add block offsets; set rowptr[N] = E ----
__global__ __launch_bounds__(256) void scan3(unsigned* __restrict__ rowptr,
                                             const unsigned* __restrict__ bsum,
                                             int N, int E) {
    int i = blockIdx.x * 256 + threadIdx.x;
    if (i < N) rowptr[i] += bsum[i / SCAN_ELEMS];
    if (i == 0) rowptr[N] = (unsigned)E;
}

// ---- CSR placement: csr_src[rowptr[d] + cursor[d]++] = src[e] ----
__global__ __launch_bounds__(256) void scatter_csr(const int* __restrict__ src,
                                                   const int* __restrict__ dst,
                                                   const unsigned* __restrict__ rowptr,
                                                   unsigned* __restrict__ cursor,
                                                   int* __restrict__ csr_src, int E) {
    int e = blockIdx.x * 256 + threadIdx.x;
    if (e >= E) return;
    int d = dst[e];
    unsigned pos = atomicAdd(&cursor[d], 1u);
    csr_src[rowptr[d] + pos] = src[e];
}

// ---- Y[N,64] = (X[N,64] @ W[64,64]) * dinv[row] ----
__global__ __launch_bounds__(256) void mm64_scaled(const float* __restrict__ X,
                                                   const float* __restrict__ W,
                                                   const float* __restrict__ dinv,
                                                   float* __restrict__ Y, int N) {
    __shared__ float Ws[64 * 64];
    __shared__ float Xs[16 * 64];
    int tid = threadIdx.x;
    for (int i = tid; i < 1024; i += 256)
        ((float4*)Ws)[i] = ((const float4*)W)[i];
    int row0 = blockIdx.x * 16;
    {
        int r = tid >> 4, c4 = tid & 15;
        int grow = row0 + r;
        float4 v = make_float4(0.f, 0.f, 0.f, 0.f);
        if (grow < N) v = ((const float4*)(X + (size_t)grow * F))[c4];
        ((float4*)Xs)[tid] = v;
    }
    __syncthreads();
    int r = tid >> 4, c = (tid & 15) * 4;
    float4 acc = make_float4(0.f, 0.f, 0.f, 0.f);
#pragma unroll
    for (int k = 0; k < 64; ++k) {
        float xv = Xs[r * 64 + k];
        float4 w = *(const float4*)&Ws[k * 64 + c];
        acc.x += xv * w.x; acc.y += xv * w.y;
        acc.z += xv * w.z; acc.w += xv * w.w;
    }
    int grow = row0 + r;
    if (grow < N) {
        float dv = dinv[grow];
        acc.x *= dv; acc.y *= dv; acc.z *= dv; acc.w *= dv;
        *(float4*)(Y + (size_t)grow * F + c) = acc;
    }
}

// ---- gather aggregation: O[v] = dinv[v]*(sum_{s in nbr(v)} g[s] + g[v]) + b ----
// 16 lanes per node (one float4 each), 16 nodes per 256-thread block.
template <int RELU>
__global__ __launch_bounds__(256) void gather_nodes(const int* __restrict__ csr_src,
                                                    const unsigned* __restrict__ rowptr,
                                                    const float* __restrict__ g,
                                                    const float* __restrict__ dinv,
                                                    const float* __restrict__ bias,
                                                    float* __restrict__ O, int N) {
    int gid = blockIdx.x * 256 + threadIdx.x;
    int v = gid >> 4;
    if (v >= N) return;
    int f4 = gid & 15;
    const float4* G = (const float4*)g;
    unsigned r0 = rowptr[v], r1 = rowptr[v + 1];
    float4 acc = G[(size_t)v * 16 + f4];  // self-loop term g[v]
    unsigned j = r0;
    for (; j + 2 <= r1; j += 2) {   // 2 outstanding gathers for latency overlap
        int s0 = csr_src[j], s1 = csr_src[j + 1];
        float4 a = G[(size_t)s0 * 16 + f4];
        float4 b = G[(size_t)s1 * 16 + f4];
        acc.x += a.x + b.x; acc.y += a.y + b.y;
        acc.z += a.z + b.z; acc.w += a.w + b.w;
    }
    if (j < r1) {
        int s = csr_src[j];
        float4 a = G[(size_t)s * 16 + f4];
        acc.x += a.x; acc.y += a.y; acc.z += a.z; acc.w += a.w;
    }
    float dv = dinv[v];
    float4 bb = ((const float4*)bias)[f4];
    float4 r;
    r.x = acc.x * dv + bb.x;
    r.y = acc.y * dv + bb.y;
    r.z = acc.z * dv + bb.z;
    r.w = acc.w * dv + bb.w;
    if (RELU) {
        r.x = fmaxf(r.x, 0.f); r.y = fmaxf(r.y, 0.f);
        r.z = fmaxf(r.z, 0.f); r.w = fmaxf(r.w, 0.f);
    }
    ((float4*)(O + (size_t)v * F))[f4] = r;
}

extern "C" void kernel_launch(void* const* d_in, const int* in_sizes, int n_in,
                              void* d_out, int out_size, void* d_ws, size_t ws_size,
                              hipStream_t stream) {
    const float* x  = (const float*)d_in[0];
    const int*   ei = (const int*)d_in[1];
    const float* W1 = (const float*)d_in[2];
    const float* b1 = (const float*)d_in[3];
    const float* W2 = (const float*)d_in[4];
    const float* b2 = (const float*)d_in[5];
    int N = in_sizes[0] / F;
    int E = in_sizes[1] / 2;
    const int* srcp = ei;
    const int* dstp = ei + E;
    float* out = (float*)d_out;

    // workspace layout (256 B aligned each)
    char* w = (char*)d_ws;
    auto align = [](size_t s) { return (s + 255) / 256 * 256; };
    size_t nU32 = align((size_t)N * 4);
    size_t nP   = align(((size_t)N + 1) * 4);
    size_t nE   = align((size_t)E * 4);
    size_t feat = align((size_t)N * F * sizeof(float));

    unsigned* cnt    = (unsigned*)w;              w += nU32;
    unsigned* cursor = (unsigned*)w;              w += nU32;
    unsigned* rowptr = (unsigned*)w;              w += nP;
    unsigned* bsum   = (unsigned*)w;              w += 256 * 4;
    int*      csrsrc = (int*)w;                   w += nE;
    float*    dinv   = (float*)w;                 w += nU32;
    float*    bufA   = (float*)w;                 w += feat;   // g (scaled features)
    float*    bufB   = (float*)w;                 /* layer-1 output */

    hipMemsetAsync(cnt, 0, (size_t)N * 4, stream);
    hipMemsetAsync(cursor, 0, (size_t)N * 4, stream);

    int nb = (N + SCAN_ELEMS - 1) / SCAN_ELEMS;  // 98 for N=100k (<=256)

    count_deg<<<(E + 255) / 256, 256, 0, stream>>>(dstp, cnt, E);
    make_dinv<<<(N + 255) / 256, 256, 0, stream>>>(cnt, dinv, N);
    scan1<<<nb, SCAN_BLOCK, 0, stream>>>(cnt, rowptr, bsum, N);
    scan2<<<1, 256, 0, stream>>>(bsum, nb);
    scan3<<<(N + 255) / 256, 256, 0, stream>>>(rowptr, bsum, N, E);
    scatter_csr<<<(E + 255) / 256, 256, 0, stream>>>(srcp, dstp, rowptr, cursor, csrsrc, E);

    // layer 1: g1 = (x@W1)*dinv ; out1 = relu(dinv*(sum g1) + b1)
    mm64_scaled<<<(N + 15) / 16, 256, 0, stream>>>(x, W1, dinv, bufA, N);
    gather_nodes<1><<<((size_t)N * 16 + 255) / 256, 256, 0, stream>>>(csrsrc, rowptr, bufA, dinv, b1, bufB, N);

    // layer 2: g2 = (out1@W2)*dinv ; out = dinv*(sum g2) + b2
    mm64_scaled<<<(N + 15) / 16, 256, 0, stream>>>(bufB, W2, dinv, bufA, N);
    gather_nodes<0><<<((size_t)N * 16 + 255) / 256, 256, 0, stream>>>(csrsrc, rowptr, bufA, dinv, b2, out, N);
}

// Round 3
// 256.626 us; speedup vs baseline: 7.4081x; 1.2750x over previous
//
#include <hip/hip_runtime.h>

#define F 64
#define NBMAX 1024   // max dst-buckets (256 nodes each) -> supports N <= 262144
#define CHUNK 4096   // edges per partition block

// ---- h1: bucket histogram (LDS-privatized) ----
__global__ __launch_bounds__(256) void bucket_hist(const int* __restrict__ dst,
                                                   unsigned* __restrict__ bhist,
                                                   int E, int NB) {
    __shared__ unsigned lh[NBMAX];
    int t = threadIdx.x;
    for (int b = t; b < NB; b += 256) lh[b] = 0;
    __syncthreads();
    for (int e = blockIdx.x * 256 + t; e < E; e += gridDim.x * 256)
        atomicAdd(&lh[((unsigned)dst[e]) >> 8], 1u);
    __syncthreads();
    for (int b = t; b < NB; b += 256)
        if (lh[b]) atomicAdd(&bhist[b], lh[b]);
}

// ---- h2: exclusive scan of bucket counts (NB <= 1024, one block) ----
__global__ __launch_bounds__(1024) void bucket_scan(const unsigned* __restrict__ bhist,
                                                    unsigned* __restrict__ bbase,
                                                    unsigned* __restrict__ bcursor,
                                                    int NB) {
    __shared__ unsigned ts[1024];
    int t = threadIdx.x;
    ts[t] = (t < NB) ? bhist[t] : 0u;
    __syncthreads();
    for (int off = 1; off < 1024; off <<= 1) {
        unsigned add = (t >= off) ? ts[t - off] : 0u;
        __syncthreads();
        ts[t] += add;
        __syncthreads();
    }
    unsigned excl = (t == 0) ? 0u : ts[t - 1];
    if (t < NB) { bbase[t] = excl; bcursor[t] = excl; }
    if (t == NB - 1) bbase[NB] = ts[t];
}

// ---- h3: partition edges into dst-buckets, packed (dstlo<<24)|src ----
__global__ __launch_bounds__(256) void partition_edges(const int* __restrict__ src,
                                                       const int* __restrict__ dst,
                                                       unsigned* __restrict__ bcursor,
                                                       unsigned* __restrict__ part,
                                                       int E, int NB) {
    __shared__ unsigned lh[NBMAX];
    __shared__ unsigned lbase[NBMAX];
    int t = threadIdx.x;
    int e0 = blockIdx.x * CHUNK;
    int e1 = min(e0 + CHUNK, E);
    for (int b = t; b < NB; b += 256) lh[b] = 0;
    __syncthreads();
    for (int e = e0 + t; e < e1; e += 256)
        atomicAdd(&lh[((unsigned)dst[e]) >> 8], 1u);
    __syncthreads();
    for (int b = t; b < NB; b += 256) {
        unsigned c = lh[b];
        lbase[b] = c ? atomicAdd(&bcursor[b], c) : 0u;
        lh[b] = 0;  // reuse as local cursor
    }
    __syncthreads();
    for (int e = e0 + t; e < e1; e += 256) {
        unsigned d = (unsigned)dst[e];
        unsigned b = d >> 8;
        unsigned pos = lbase[b] + atomicAdd(&lh[b], 1u);
        part[pos] = ((d & 255u) << 24) | (unsigned)src[e];  // src < 2^24
    }
}

// ---- h4: per-bucket CSR build; emits rowptr, dinv, csr_src (localized writes) ----
__global__ __launch_bounds__(256) void build_bucket(const unsigned* __restrict__ part,
                                                    const unsigned* __restrict__ bbase,
                                                    unsigned* __restrict__ rowptr,
                                                    float* __restrict__ dinv,
                                                    int* __restrict__ csr_src,
                                                    int N, int E) {
    __shared__ unsigned cnt[256], off[256], cur[256];
    int t = threadIdx.x;
    int b = blockIdx.x;
    unsigned m0 = bbase[b], m1 = bbase[b + 1];
    cnt[t] = 0;
    __syncthreads();
    for (unsigned j = m0 + t; j < m1; j += 256)
        atomicAdd(&cnt[part[j] >> 24], 1u);
    __syncthreads();
    // inclusive scan into off
    off[t] = cnt[t];
    __syncthreads();
    for (int o = 1; o < 256; o <<= 1) {
        unsigned add = (t >= o) ? off[t - o] : 0u;
        __syncthreads();
        off[t] += add;
        __syncthreads();
    }
    unsigned excl = (t == 0) ? 0u : off[t - 1];
    __syncthreads();
    off[t] = excl;   // exclusive scan, shared for pass B
    cur[t] = 0;
    int v = (b << 8) + t;
    if (v < N) {
        rowptr[v] = m0 + excl;
        dinv[v] = rsqrtf((float)(cnt[t] + 1u));
    }
    if (b == 0 && t == 0) rowptr[N] = (unsigned)E;
    __syncthreads();
    for (unsigned j = m0 + t; j < m1; j += 256) {
        unsigned p = part[j];
        unsigned d = p >> 24;
        unsigned pos = atomicAdd(&cur[d], 1u);
        csr_src[m0 + off[d] + pos] = (int)(p & 0xFFFFFFu);
    }
}

// ---- Y[N,64] = (X[N,64] @ W[64,64]) * dinv[row] ----
__global__ __launch_bounds__(256) void mm64_scaled(const float* __restrict__ X,
                                                   const float* __restrict__ W,
                                                   const float* __restrict__ dinv,
                                                   float* __restrict__ Y, int N) {
    __shared__ float Ws[64 * 64];
    __shared__ float Xs[16 * 64];
    int tid = threadIdx.x;
    for (int i = tid; i < 1024; i += 256)
        ((float4*)Ws)[i] = ((const float4*)W)[i];
    int row0 = blockIdx.x * 16;
    {
        int r = tid >> 4, c4 = tid & 15;
        int grow = row0 + r;
        float4 v = make_float4(0.f, 0.f, 0.f, 0.f);
        if (grow < N) v = ((const float4*)(X + (size_t)grow * F))[c4];
        ((float4*)Xs)[tid] = v;
    }
    __syncthreads();
    int r = tid >> 4, c = (tid & 15) * 4;
    float4 acc = make_float4(0.f, 0.f, 0.f, 0.f);
#pragma unroll
    for (int k = 0; k < 64; ++k) {
        float xv = Xs[r * 64 + k];
        float4 w = *(const float4*)&Ws[k * 64 + c];
        acc.x += xv * w.x; acc.y += xv * w.y;
        acc.z += xv * w.z; acc.w += xv * w.w;
    }
    int grow = row0 + r;
    if (grow < N) {
        float dv = dinv[grow];
        acc.x *= dv; acc.y *= dv; acc.z *= dv; acc.w *= dv;
        *(float4*)(Y + (size_t)grow * F + c) = acc;
    }
}

// ---- gather aggregation: O[v] = dinv[v]*(sum_{s in nbr(v)} g[s] + g[v]) + b ----
template <int RELU>
__global__ __launch_bounds__(256) void gather_nodes(const int* __restrict__ csr_src,
                                                    const unsigned* __restrict__ rowptr,
                                                    const float* __restrict__ g,
                                                    const float* __restrict__ dinv,
                                                    const float* __restrict__ bias,
                                                    float* __restrict__ O, int N) {
    int gid = blockIdx.x * 256 + threadIdx.x;
    int v = gid >> 4;
    if (v >= N) return;
    int f4 = gid & 15;
    const float4* G = (const float4*)g;
    unsigned r0 = rowptr[v], r1 = rowptr[v + 1];
    float4 acc = G[(size_t)v * 16 + f4];  // self-loop term g[v]
    unsigned j = r0;
    for (; j + 2 <= r1; j += 2) {
        int s0 = csr_src[j], s1 = csr_src[j + 1];
        float4 a = G[(size_t)s0 * 16 + f4];
        float4 b = G[(size_t)s1 * 16 + f4];
        acc.x += a.x + b.x; acc.y += a.y + b.y;
        acc.z += a.z + b.z; acc.w += a.w + b.w;
    }
    if (j < r1) {
        int s = csr_src[j];
        float4 a = G[(size_t)s * 16 + f4];
        acc.x += a.x; acc.y += a.y; acc.z += a.z; acc.w += a.w;
    }
    float dv = dinv[v];
    float4 bb = ((const float4*)bias)[f4];
    float4 r;
    r.x = acc.x * dv + bb.x;
    r.y = acc.y * dv + bb.y;
    r.z = acc.z * dv + bb.z;
    r.w = acc.w * dv + bb.w;
    if (RELU) {
        r.x = fmaxf(r.x, 0.f); r.y = fmaxf(r.y, 0.f);
        r.z = fmaxf(r.z, 0.f); r.w = fmaxf(r.w, 0.f);
    }
    ((float4*)(O + (size_t)v * F))[f4] = r;
}

extern "C" void kernel_launch(void* const* d_in, const int* in_sizes, int n_in,
                              void* d_out, int out_size, void* d_ws, size_t ws_size,
                              hipStream_t stream) {
    const float* x  = (const float*)d_in[0];
    const int*   ei = (const int*)d_in[1];
    const float* W1 = (const float*)d_in[2];
    const float* b1 = (const float*)d_in[3];
    const float* W2 = (const float*)d_in[4];
    const float* b2 = (const float*)d_in[5];
    int N = in_sizes[0] / F;
    int E = in_sizes[1] / 2;
    const int* srcp = ei;
    const int* dstp = ei + E;
    float* out = (float*)d_out;
    int NB = (N + 255) >> 8;   // 391 for N=100k

    // workspace layout (256 B aligned)
    char* w = (char*)d_ws;
    auto align = [](size_t s) { return (s + 255) / 256 * 256; };
    unsigned* bhist   = (unsigned*)w;  w += align(NBMAX * 4);
    unsigned* bbase   = (unsigned*)w;  w += align((NBMAX + 1) * 4);
    unsigned* bcursor = (unsigned*)w;  w += align(NBMAX * 4);
    unsigned* part    = (unsigned*)w;  w += align((size_t)E * 4);
    int*      csrsrc  = (int*)w;       w += align((size_t)E * 4);
    unsigned* rowptr  = (unsigned*)w;  w += align(((size_t)N + 1) * 4);
    float*    dinv    = (float*)w;     w += align((size_t)N * 4);
    float*    bufA    = (float*)w;     w += align((size_t)N * F * 4);  // g
    float*    bufB    = (float*)w;     // layer-1 output

    hipMemsetAsync(bhist, 0, (size_t)NB * 4, stream);

    bucket_hist<<<256, 256, 0, stream>>>(dstp, bhist, E, NB);
    bucket_scan<<<1, 1024, 0, stream>>>(bhist, bbase, bcursor, NB);
    partition_edges<<<(E + CHUNK - 1) / CHUNK, 256, 0, stream>>>(srcp, dstp, bcursor, part, E, NB);
    build_bucket<<<NB, 256, 0, stream>>>(part, bbase, rowptr, dinv, csrsrc, N, E);

    // layer 1: g1 = (x@W1)*dinv ; out1 = relu(dinv*(sum g1) + b1)
    mm64_scaled<<<(N + 15) / 16, 256, 0, stream>>>(x, W1, dinv, bufA, N);
    gather_nodes<1><<<((size_t)N * 16 + 255) / 256, 256, 0, stream>>>(csrsrc, rowptr, bufA, dinv, b1, bufB, N);

    // layer 2: g2 = (out1@W2)*dinv ; out = dinv*(sum g2) + b2
    mm64_scaled<<<(N + 15) / 16, 256, 0, stream>>>(bufB, W2, dinv, bufA, N);
    gather_nodes<0><<<((size_t)N * 16 + 255) / 256, 256, 0, stream>>>(csrsrc, rowptr, bufA, dinv, b2, out, N);
}

// Round 4
// 225.200 us; speedup vs baseline: 8.4419x; 1.1395x over previous
//
#include <hip/hip_runtime.h>
#include <hip/hip_fp16.h>

#define F 64
#define NBMAX 1024   // max dst-buckets (256 nodes each) -> supports N <= 262144
#define CHUNK 4096   // edges per partition block

// ---- h1: bucket histogram (LDS-privatized) ----
__global__ __launch_bounds__(256) void bucket_hist(const int* __restrict__ dst,
                                                   unsigned* __restrict__ bhist,
                                                   int E, int NB) {
    __shared__ unsigned lh[NBMAX];
    int t = threadIdx.x;
    for (int b = t; b < NB; b += 256) lh[b] = 0;
    __syncthreads();
    for (int e = blockIdx.x * 256 + t; e < E; e += gridDim.x * 256)
        atomicAdd(&lh[((unsigned)dst[e]) >> 8], 1u);
    __syncthreads();
    for (int b = t; b < NB; b += 256)
        if (lh[b]) atomicAdd(&bhist[b], lh[b]);
}

// ---- h2: exclusive scan of bucket counts (NB <= 1024, one block) ----
__global__ __launch_bounds__(1024) void bucket_scan(const unsigned* __restrict__ bhist,
                                                    unsigned* __restrict__ bbase,
                                                    unsigned* __restrict__ bcursor,
                                                    int NB) {
    __shared__ unsigned ts[1024];
    int t = threadIdx.x;
    ts[t] = (t < NB) ? bhist[t] : 0u;
    __syncthreads();
    for (int off = 1; off < 1024; off <<= 1) {
        unsigned add = (t >= off) ? ts[t - off] : 0u;
        __syncthreads();
        ts[t] += add;
        __syncthreads();
    }
    unsigned excl = (t == 0) ? 0u : ts[t - 1];
    if (t < NB) { bbase[t] = excl; bcursor[t] = excl; }
    if (t == NB - 1) bbase[NB] = ts[t];
}

// ---- h3: partition edges into dst-buckets, packed (dstlo<<24)|src ----
__global__ __launch_bounds__(256) void partition_edges(const int* __restrict__ src,
                                                       const int* __restrict__ dst,
                                                       unsigned* __restrict__ bcursor,
                                                       unsigned* __restrict__ part,
                                                       int E, int NB) {
    __shared__ unsigned lh[NBMAX];
    __shared__ unsigned lbase[NBMAX];
    int t = threadIdx.x;
    int e0 = blockIdx.x * CHUNK;
    int e1 = min(e0 + CHUNK, E);
    for (int b = t; b < NB; b += 256) lh[b] = 0;
    __syncthreads();
    for (int e = e0 + t; e < e1; e += 256)
        atomicAdd(&lh[((unsigned)dst[e]) >> 8], 1u);
    __syncthreads();
    for (int b = t; b < NB; b += 256) {
        unsigned c = lh[b];
        lbase[b] = c ? atomicAdd(&bcursor[b], c) : 0u;
        lh[b] = 0;  // reuse as local cursor
    }
    __syncthreads();
    for (int e = e0 + t; e < e1; e += 256) {
        unsigned d = (unsigned)dst[e];
        unsigned b = d >> 8;
        unsigned pos = lbase[b] + atomicAdd(&lh[b], 1u);
        part[pos] = ((d & 255u) << 24) | (unsigned)src[e];  // src < 2^24
    }
}

// ---- h4: per-bucket CSR build; emits rowptr, dinv, csr_src (localized writes) ----
__global__ __launch_bounds__(256) void build_bucket(const unsigned* __restrict__ part,
                                                    const unsigned* __restrict__ bbase,
                                                    unsigned* __restrict__ rowptr,
                                                    float* __restrict__ dinv,
                                                    int* __restrict__ csr_src,
                                                    int N, int E) {
    __shared__ unsigned cnt[256], off[256], cur[256];
    int t = threadIdx.x;
    int b = blockIdx.x;
    unsigned m0 = bbase[b], m1 = bbase[b + 1];
    cnt[t] = 0;
    __syncthreads();
    for (unsigned j = m0 + t; j < m1; j += 256)
        atomicAdd(&cnt[part[j] >> 24], 1u);
    __syncthreads();
    off[t] = cnt[t];
    __syncthreads();
    for (int o = 1; o < 256; o <<= 1) {
        unsigned add = (t >= o) ? off[t - o] : 0u;
        __syncthreads();
        off[t] += add;
        __syncthreads();
    }
    unsigned excl = (t == 0) ? 0u : off[t - 1];
    __syncthreads();
    off[t] = excl;
    cur[t] = 0;
    int v = (b << 8) + t;
    if (v < N) {
        rowptr[v] = m0 + excl;
        dinv[v] = rsqrtf((float)(cnt[t] + 1u));
    }
    if (b == 0 && t == 0) rowptr[N] = (unsigned)E;
    __syncthreads();
    for (unsigned j = m0 + t; j < m1; j += 256) {
        unsigned p = part[j];
        unsigned d = p >> 24;
        unsigned pos = atomicAdd(&cur[d], 1u);
        csr_src[m0 + off[d] + pos] = (int)(p & 0xFFFFFFu);
    }
}

// ---- Y[N,64](f16) = (X[N,64] @ W[64,64]) * dinv[row] ----
// 256 threads = 32 ty x 8 tx; thread computes 4 rows x 8 cols; 128 rows/block.
// X staged TRANSPOSED in LDS (pad 132) so k-loop is 3x ds_read_b128 per 32 FMA.
#define MMROWS 128
#define XT_PAD 132
__global__ __launch_bounds__(256) void mm64_f16(const float* __restrict__ X,
                                                const float* __restrict__ W,
                                                const float* __restrict__ dinv,
                                                __half2* __restrict__ Y, int N) {
    __shared__ float Ws[64 * 64];       // 16 KB
    __shared__ float XT[64 * XT_PAD];   // X^T tile [k][r], 33 KB
    int t = threadIdx.x;
    for (int i = t; i < 1024; i += 256)
        ((float4*)Ws)[i] = ((const float4*)W)[i];
    int row0 = blockIdx.x * MMROWS;
    for (int i = t; i < MMROWS * 16; i += 256) {
        int r = i >> 4, kc = (i & 15) * 4;
        float4 v = make_float4(0.f, 0.f, 0.f, 0.f);
        int gr = row0 + r;
        if (gr < N) v = *(const float4*)(X + (size_t)gr * F + kc);
        XT[(kc + 0) * XT_PAD + r] = v.x;
        XT[(kc + 1) * XT_PAD + r] = v.y;
        XT[(kc + 2) * XT_PAD + r] = v.z;
        XT[(kc + 3) * XT_PAD + r] = v.w;
    }
    __syncthreads();
    int ty = t >> 3, tx = t & 7;
    float acc[4][8];
#pragma unroll
    for (int i = 0; i < 4; ++i)
#pragma unroll
        for (int j = 0; j < 8; ++j) acc[i][j] = 0.f;
#pragma unroll 4
    for (int k = 0; k < 64; ++k) {
        float4 xr = *(const float4*)&XT[k * XT_PAD + ty * 4];
        float4 w0 = *(const float4*)&Ws[k * 64 + tx * 8];
        float4 w1 = *(const float4*)&Ws[k * 64 + tx * 8 + 4];
        const float* xv = &xr.x;
#pragma unroll
        for (int i = 0; i < 4; ++i) {
            float xs = xv[i];
            acc[i][0] += xs * w0.x; acc[i][1] += xs * w0.y;
            acc[i][2] += xs * w0.z; acc[i][3] += xs * w0.w;
            acc[i][4] += xs * w1.x; acc[i][5] += xs * w1.y;
            acc[i][6] += xs * w1.z; acc[i][7] += xs * w1.w;
        }
    }
#pragma unroll
    for (int i = 0; i < 4; ++i) {
        int gr = row0 + ty * 4 + i;
        if (gr >= N) continue;
        float dv = dinv[gr];
        __half2 h[4];
#pragma unroll
        for (int j = 0; j < 4; ++j)
            h[j] = __floats2half2_rn(acc[i][2 * j] * dv, acc[i][2 * j + 1] * dv);
        // 16 B store: row gr, cols tx*8..tx*8+7
        *reinterpret_cast<uint4*>(Y + (size_t)gr * 32 + tx * 4) =
            *reinterpret_cast<uint4*>(h);
    }
}

// ---- gather (f16 g): O[v] = dinv[v]*(sum_{s in nbr(v)} g[s] + g[v]) + b ----
// 16 lanes per node, 8 B (4 halves) per lane; fp32 accumulate; 4x unroll.
template <int RELU>
__global__ __launch_bounds__(256) void gather_f16(const int* __restrict__ csr_src,
                                                  const unsigned* __restrict__ rowptr,
                                                  const uint2* __restrict__ G,
                                                  const float* __restrict__ dinv,
                                                  const float* __restrict__ bias,
                                                  float* __restrict__ O, int N) {
    int gid = blockIdx.x * 256 + threadIdx.x;
    int v = gid >> 4;
    if (v >= N) return;
    int f4 = gid & 15;
    unsigned r0 = rowptr[v], r1 = rowptr[v + 1];
    float4 acc = make_float4(0.f, 0.f, 0.f, 0.f);
    {
        uint2 u = G[(size_t)v * 16 + f4];  // self-loop term
        __half2 h0 = *reinterpret_cast<__half2*>(&u.x);
        __half2 h1 = *reinterpret_cast<__half2*>(&u.y);
        float2 f0 = __half22float2(h0), f1 = __half22float2(h1);
        acc.x += f0.x; acc.y += f0.y; acc.z += f1.x; acc.w += f1.y;
    }
    unsigned j = r0;
    for (; j + 4 <= r1; j += 4) {
        int s0 = csr_src[j], s1 = csr_src[j + 1];
        int s2 = csr_src[j + 2], s3 = csr_src[j + 3];
        uint2 a = G[(size_t)s0 * 16 + f4];
        uint2 b = G[(size_t)s1 * 16 + f4];
        uint2 c = G[(size_t)s2 * 16 + f4];
        uint2 d = G[(size_t)s3 * 16 + f4];
#define ACCUM(u) { \
        __half2 h0 = *reinterpret_cast<__half2*>(&u.x); \
        __half2 h1 = *reinterpret_cast<__half2*>(&u.y); \
        float2 f0 = __half22float2(h0), f1 = __half22float2(h1); \
        acc.x += f0.x; acc.y += f0.y; acc.z += f1.x; acc.w += f1.y; }
        ACCUM(a) ACCUM(b) ACCUM(c) ACCUM(d)
    }
    for (; j < r1; ++j) {
        uint2 a = G[(size_t)csr_src[j] * 16 + f4];
        ACCUM(a)
    }
#undef ACCUM
    float dv = dinv[v];
    float4 bb = ((const float4*)bias)[f4];
    float4 r;
    r.x = acc.x * dv + bb.x;
    r.y = acc.y * dv + bb.y;
    r.z = acc.z * dv + bb.z;
    r.w = acc.w * dv + bb.w;
    if (RELU) {
        r.x = fmaxf(r.x, 0.f); r.y = fmaxf(r.y, 0.f);
        r.z = fmaxf(r.z, 0.f); r.w = fmaxf(r.w, 0.f);
    }
    ((float4*)(O + (size_t)v * F))[f4] = r;
}

extern "C" void kernel_launch(void* const* d_in, const int* in_sizes, int n_in,
                              void* d_out, int out_size, void* d_ws, size_t ws_size,
                              hipStream_t stream) {
    const float* x  = (const float*)d_in[0];
    const int*   ei = (const int*)d_in[1];
    const float* W1 = (const float*)d_in[2];
    const float* b1 = (const float*)d_in[3];
    const float* W2 = (const float*)d_in[4];
    const float* b2 = (const float*)d_in[5];
    int N = in_sizes[0] / F;
    int E = in_sizes[1] / 2;
    const int* srcp = ei;
    const int* dstp = ei + E;
    float* out = (float*)d_out;
    int NB = (N + 255) >> 8;

    char* w = (char*)d_ws;
    auto align = [](size_t s) { return (s + 255) / 256 * 256; };
    unsigned* bhist   = (unsigned*)w;  w += align(NBMAX * 4);
    unsigned* bbase   = (unsigned*)w;  w += align((NBMAX + 1) * 4);
    unsigned* bcursor = (unsigned*)w;  w += align(NBMAX * 4);
    unsigned* part    = (unsigned*)w;  w += align((size_t)E * 4);
    int*      csrsrc  = (int*)w;       w += align((size_t)E * 4);
    unsigned* rowptr  = (unsigned*)w;  w += align(((size_t)N + 1) * 4);
    float*    dinv    = (float*)w;     w += align((size_t)N * 4);
    __half2*  bufA    = (__half2*)w;   w += align((size_t)N * F * 2);  // g (f16)
    float*    bufB    = (float*)w;     // layer-1 output (fp32)

    hipMemsetAsync(bhist, 0, (size_t)NB * 4, stream);

    bucket_hist<<<256, 256, 0, stream>>>(dstp, bhist, E, NB);
    bucket_scan<<<1, 1024, 0, stream>>>(bhist, bbase, bcursor, NB);
    partition_edges<<<(E + CHUNK - 1) / CHUNK, 256, 0, stream>>>(srcp, dstp, bcursor, part, E, NB);
    build_bucket<<<NB, 256, 0, stream>>>(part, bbase, rowptr, dinv, csrsrc, N, E);

    int mmGrid = (N + MMROWS - 1) / MMROWS;
    // layer 1
    mm64_f16<<<mmGrid, 256, 0, stream>>>(x, W1, dinv, bufA, N);
    gather_f16<1><<<((size_t)N * 16 + 255) / 256, 256, 0, stream>>>(csrsrc, rowptr, (const uint2*)bufA, dinv, b1, bufB, N);
    // layer 2
    mm64_f16<<<mmGrid, 256, 0, stream>>>(bufB, W2, dinv, bufA, N);
    gather_f16<0><<<((size_t)N * 16 + 255) / 256, 256, 0, stream>>>(csrsrc, rowptr, (const uint2*)bufA, dinv, b2, out, N);
}